// Round 7
// baseline (276.099 us; speedup 1.0000x reference)
//
#include <hip/hip_runtime.h>
#include <math.h>

// ---------------------------------------------------------------------------
// PatientDistillation: three losses.
//  out[0] = train_loss (CE over s_logits/labels)
//  out[1] = soft_loss  (KL(batchmean) at temperature T, * T^2)
//  out[2] = distill_loss (sum over rows of k smallest same-label sq dists / D)
//
// R6 lesson: GEMM iter time is pinned by per-CU vmem BYTES (the 2x2 block
// grid stages every row twice -> 384 MB through vmem at ~6.4 B/cyc/CU), not
// by in-flight depth or DMA scheme. R7: ONE 256x256 macro-tile per z-slice
// (1024 threads, 16 waves) -> every element staged exactly once (192 MB),
// bf16 LDS staging (register RNE pack; frag reads = single ds_read_b128),
// 64 KB dbuf LDS, register prefetch (64 KB in flight/block). Residual ~170us
// across R1-R6 is harness-fixed (input restore), not kernel time.
// ---------------------------------------------------------------------------

#define BMAC 256        // macro tile (covers all of B)
#define BKF  32         // k-elems per stage; one 16x16x32 MFMA k-step
#define LP   32         // LDS pitch in bf16 elems (64 B row, 4 16B groups)
#define ST   (BMAC * LP)   // bf16 elems per matrix per stage (8192 = 16 KB)

typedef __attribute__((ext_vector_type(8))) short short8;   // 8 bf16 = 4 VGPR
typedef __attribute__((ext_vector_type(4))) float f32x4;

__device__ inline unsigned pack_bf16(float a, float b) {
    // round-to-nearest-even f32 -> bf16, packed pair
    unsigned ua = __float_as_uint(a), ub = __float_as_uint(b);
    ua = (ua + 0x7fffu + ((ua >> 16) & 1u)) >> 16;
    ub = (ub + 0x7fffu + ((ub >> 16) & 1u)) >> 16;
    return (ua & 0xffffu) | (ub << 16);
}

// ---------------- MFMA GEMM: one 256x256 tile per z-slice ------------------
// grid (gz); 1024 threads = 16 waves in 4x4; wave (wm,wn) owns a 64x64
// quadrant as 4x4 tiles of 16x16x32 bf16 MFMA. Staging: thread (r=tid>>2,
// g=tid&3) loads rows r cols g*8..g*8+7 (f32, coalesced 128 B per 4 lanes),
// RNE-packs to bf16, writes one uint4 to LDS at swizzled group g^(r&3).
// Dbuf: write stage p | issue loads p+1 | barrier | compute p.
__global__ __launch_bounds__(1024) void gemm_dot_kernel(const float* __restrict__ S,
                                                        const float* __restrict__ T,
                                                        float* __restrict__ part,   // [gz][B*B]
                                                        float* __restrict__ spart,  // [gz][B]
                                                        float* __restrict__ tpart,  // [gz][B]
                                                        int* __restrict__ counter,
                                                        int B, int K, int KC) {
    extern __shared__ __align__(16) unsigned short smem[];  // 2*(As|Bs) = 64 KB

    const int tid  = threadIdx.x;
    const int bz   = blockIdx.x;
    const int kbeg = bz * KC;
    const int iters = KC / BKF;

    if (bz == 0 && tid == 0) *counter = 0;   // replaces memset dispatch

    // ---- staging coords
    const int r = tid >> 2;          // row 0..255
    const int g = tid & 3;           // 16B-group 0..3 (8 f32 source cols)
    int gi = r < B ? r : B - 1;      // clamp: harmless duplicate loads
    const float* srcS = S + (size_t)gi * K + kbeg + g * 8;
    const float* srcT = T + (size_t)gi * K + kbeg + g * 8;
    const int woff = r * LP + ((g ^ (r & 3)) * 8);   // bf16 elem offset

    // ---- frag coords
    const int lane = tid & 63;
    const int wid  = tid >> 6;       // 0..15
    const int wm   = wid >> 2;
    const int wn   = wid & 3;
    const int l15  = lane & 15;
    const int quad = lane >> 4;
    const int xq   = (quad ^ (l15 & 3)) * 8;   // swizzled k-group offset
    int aoff[4], boff[4];
    #pragma unroll
    for (int t = 0; t < 4; ++t) {
        aoff[t] = (wm * 64 + t * 16 + l15) * LP + xq;
        boff[t] = (wn * 64 + t * 16 + l15) * LP + xq;
    }

    f32x4 acc[4][4] = {};
    float pns = 0.f, pnt = 0.f;

    // ---- prologue loads (stage 0)
    f32x4 s0 = *(const f32x4*)srcS;
    f32x4 s1 = *(const f32x4*)(srcS + 4);
    f32x4 t0 = *(const f32x4*)srcT;
    f32x4 t1 = *(const f32x4*)(srcT + 4);

    for (int it = 0; it < iters; ++it) {
        unsigned short* As = smem + (it & 1) * 2 * ST;
        unsigned short* Bs = As + ST;

        // ---- norms from register values (pre-pack), then stage to LDS
        pns += s0.x*s0.x + s0.y*s0.y + s0.z*s0.z + s0.w*s0.w
             + s1.x*s1.x + s1.y*s1.y + s1.z*s1.z + s1.w*s1.w;
        pnt += t0.x*t0.x + t0.y*t0.y + t0.z*t0.z + t0.w*t0.w
             + t1.x*t1.x + t1.y*t1.y + t1.z*t1.z + t1.w*t1.w;
        uint4 pa = make_uint4(pack_bf16(s0.x, s0.y), pack_bf16(s0.z, s0.w),
                              pack_bf16(s1.x, s1.y), pack_bf16(s1.z, s1.w));
        uint4 pb = make_uint4(pack_bf16(t0.x, t0.y), pack_bf16(t0.z, t0.w),
                              pack_bf16(t1.x, t1.y), pack_bf16(t1.z, t1.w));
        *(uint4*)&As[woff] = pa;
        *(uint4*)&Bs[woff] = pb;

        // ---- issue next stage's loads (land during this compute phase)
        if (it + 1 < iters) {
            const float* nS = srcS + (it + 1) * BKF;
            const float* nT = srcT + (it + 1) * BKF;
            s0 = *(const f32x4*)nS;
            s1 = *(const f32x4*)(nS + 4);
            t0 = *(const f32x4*)nT;
            t1 = *(const f32x4*)(nT + 4);
        }

        __syncthreads();   // stage visible to all; prev stage's reads done
                           // (write targets alternate stage each iter)

        // ---- compute: 4x4 tiles of 16x16x32
        short8 bfr[4];
        #pragma unroll
        for (int ni = 0; ni < 4; ++ni)
            bfr[ni] = *(const short8*)&Bs[boff[ni]];
        #pragma unroll
        for (int mi = 0; mi < 4; ++mi) {
            short8 afr = *(const short8*)&As[aoff[mi]];
            #pragma unroll
            for (int ni = 0; ni < 4; ++ni)
                acc[mi][ni] = __builtin_amdgcn_mfma_f32_16x16x32_bf16(
                    afr, bfr[ni], acc[mi][ni], 0, 0, 0);
        }
    }

    // ---- dot partials: plain stores ----
    // C/D layout (16x16x32): col = lane&15, row = (lane>>4)*4 + reg
    float* outp = part + (size_t)bz * B * B;
    #pragma unroll
    for (int mi = 0; mi < 4; ++mi) {
        #pragma unroll
        for (int ni = 0; ni < 4; ++ni) {
            #pragma unroll
            for (int rr = 0; rr < 4; ++rr) {
                const int ig = wm * 64 + mi * 16 + quad * 4 + rr;
                const int jg = wn * 64 + ni * 16 + l15;
                if (ig < B && jg < B)
                    outp[(size_t)ig * B + jg] = acc[mi][ni][rr];
            }
        }
    }

    // ---- norm partials: reduce the 4 g-lanes of each row, one store ----
    {
        float v = pns;
        v += __shfl_xor(v, 1, 64);
        v += __shfl_xor(v, 2, 64);
        if ((tid & 3) == 0 && r < B) spart[(size_t)bz * B + r] = v;
        float w = pnt;
        w += __shfl_xor(w, 1, 64);
        w += __shfl_xor(w, 2, 64);
        if ((tid & 3) == 0 && r < B) tpart[(size_t)bz * B + r] = w;
    }
}

// ---------------- tail: z-reduce + norms + topk + CE/KL, one kernel --------
// grid = B blocks; block i handles row i. Thread j reduces part[:,i,j] with
// unroll-8 pipelined loads. Last block to finish finalizes out[0..2].
__global__ __launch_bounds__(256) void tail_kernel(const float* __restrict__ part,
                                                   const float* __restrict__ spart,
                                                   const float* __restrict__ tpart,
                                                   const float* __restrict__ t_logits,
                                                   const float* __restrict__ s_logits,
                                                   const int* __restrict__ labels,
                                                   const int* __restrict__ kp,
                                                   const int* __restrict__ tp,
                                                   float* __restrict__ rowsum,
                                                   int* __restrict__ counter,
                                                   float* __restrict__ out,
                                                   int B, int K, int NL, int gz) {
    const int i   = blockIdx.x;
    const int tid = threadIdx.x;
    const size_t BB = (size_t)B * B;

    __shared__ float svals[256];
    __shared__ float rv[256];
    __shared__ int   ri[256];
    __shared__ float red[4];
    __shared__ float snv;
    __shared__ int   lastf;

    // ---- s_nrm_i: threads cooperate over z
    float sp = 0.f;
    for (int z = tid; z < gz; z += 256) sp += spart[(size_t)z * B + i];
    #pragma unroll
    for (int off = 32; off > 0; off >>= 1) sp += __shfl_down(sp, off, 64);
    if ((tid & 63) == 0) red[tid >> 6] = sp;
    __syncthreads();
    if (tid == 0) snv = red[0] + red[1] + red[2] + red[3];
    __syncthreads();
    const float sn = snv;

    // ---- dt_j, tn_j: unroll-8 z-reduction (pipelined independent loads)
    float v = INFINITY;
    if (tid < B) {
        const float* pp = part + (size_t)i * B + tid;
        const float* tq = tpart + tid;
        float d0=0.f,d1=0.f,d2=0.f,d3=0.f,d4=0.f,d5=0.f,d6=0.f,d7=0.f;
        float tn = 0.f;
        int z = 0;
        for (; z + 8 <= gz; z += 8) {
            d0 += pp[(size_t)(z+0) * BB];
            d1 += pp[(size_t)(z+1) * BB];
            d2 += pp[(size_t)(z+2) * BB];
            d3 += pp[(size_t)(z+3) * BB];
            d4 += pp[(size_t)(z+4) * BB];
            d5 += pp[(size_t)(z+5) * BB];
            d6 += pp[(size_t)(z+6) * BB];
            d7 += pp[(size_t)(z+7) * BB];
            tn += tq[(size_t)(z+0) * B] + tq[(size_t)(z+1) * B]
                + tq[(size_t)(z+2) * B] + tq[(size_t)(z+3) * B]
                + tq[(size_t)(z+4) * B] + tq[(size_t)(z+5) * B]
                + tq[(size_t)(z+6) * B] + tq[(size_t)(z+7) * B];
        }
        float dt = ((d0+d1)+(d2+d3)) + ((d4+d5)+(d6+d7));
        for (; z < gz; ++z) {
            dt += pp[(size_t)z * BB];
            tn += tq[(size_t)z * B];
        }
        if (labels[i] == labels[tid])
            v = fmaxf(sn + tn - 2.0f * dt, 0.0f);
    }
    svals[tid] = v;
    __syncthreads();

    // ---- top-k smallest via LDS tournament
    const int k = kp[0];
    float sum = 0.0f;
    for (int it = 0; it < k; ++it) {
        rv[tid] = svals[tid];
        ri[tid] = tid;
        __syncthreads();
        #pragma unroll
        for (int s = 128; s > 0; s >>= 1) {
            if (tid < s) {
                if (rv[tid + s] < rv[tid]) { rv[tid] = rv[tid + s]; ri[tid] = ri[tid + s]; }
            }
            __syncthreads();
        }
        if (tid == 0) {
            if (rv[0] < 3.0e38f) sum += rv[0];
            svals[ri[0]] = INFINITY;
        }
        __syncthreads();
    }

    if (tid == 0) {
        rowsum[i] = sum;
        __threadfence();
        lastf = (atomicAdd(counter, 1) == B - 1) ? 1 : 0;
    }
    __syncthreads();
    if (!lastf) return;

    // ---- last block: finalize all three losses ----
    __threadfence();
    const float Tv = (float)tp[0];
    float rs = (tid < B) ? rowsum[tid] : 0.f;
    float ce = 0.0f, kl = 0.0f;
    for (int s = tid; s < B; s += 256) {
        const float* sl = s_logits + (size_t)s * NL;
        const float* tl = t_logits + (size_t)s * NL;
        float mx = -INFINITY;
        for (int c = 0; c < NL; ++c) mx = fmaxf(mx, sl[c]);
        float se = 0.0f;
        for (int c = 0; c < NL; ++c) se += expf(sl[c] - mx);
        ce += logf(se) + mx - sl[labels[s]];

        float mxs = -INFINITY, mxt = -INFINITY;
        for (int c = 0; c < NL; ++c) {
            mxs = fmaxf(mxs, sl[c] / Tv);
            mxt = fmaxf(mxt, tl[c] / Tv);
        }
        float ses = 0.0f, set = 0.0f;
        for (int c = 0; c < NL; ++c) {
            ses += expf(sl[c] / Tv - mxs);
            set += expf(tl[c] / Tv - mxt);
        }
        float lses = logf(ses) + mxs;
        float lset = logf(set) + mxt;
        for (int c = 0; c < NL; ++c) {
            float lst = tl[c] / Tv - lset;
            float ls  = sl[c] / Tv - lses;
            kl += expf(lst) * (lst - ls);
        }
    }
    #pragma unroll
    for (int off = 32; off > 0; off >>= 1) {
        ce += __shfl_down(ce, off, 64);
        kl += __shfl_down(kl, off, 64);
        rs += __shfl_down(rs, off, 64);
    }
    __shared__ float wce[4], wkl[4], wrs[4];
    if ((tid & 63) == 0) { wce[tid >> 6] = ce; wkl[tid >> 6] = kl; wrs[tid >> 6] = rs; }
    __syncthreads();
    if (tid == 0) {
        out[0] = (wce[0] + wce[1] + wce[2] + wce[3]) / (float)B;
        out[1] = (wkl[0] + wkl[1] + wkl[2] + wkl[3]) / (float)B * Tv * Tv;
        out[2] = (wrs[0] + wrs[1] + wrs[2] + wrs[3]) / (float)K;
    }
}

// ---------------------------------------------------------------------------
extern "C" void kernel_launch(void* const* d_in, const int* in_sizes, int n_in,
                              void* d_out, int out_size, void* d_ws, size_t ws_size,
                              hipStream_t stream) {
    const float* t_logits = (const float*)d_in[0];
    const float* s_logits = (const float*)d_in[1];
    const float* t_feat   = (const float*)d_in[2];
    const float* s_feat   = (const float*)d_in[3];
    const int*   labels   = (const int*)d_in[4];
    const int*   kp       = (const int*)d_in[5];
    const int*   tp       = (const int*)d_in[6];
    float* out = (float*)d_out;

    const int B  = in_sizes[4];          // 256
    const int NL = in_sizes[0] / B;      // 2
    const int K  = in_sizes[2] / B;      // S*H = 98304
    const size_t BB = (size_t)B * B;

    // split-K: largest gz (<=256 = 1 block/CU) with K % (gz*BKF) == 0 and all
    // workspace buffers fitting in ws.
    const size_t avail = ws_size / 4;
    const int cands[] = {256, 192, 128, 96, 64, 48, 32, 24, 16, 12, 8, 6, 4};
    int gz = 4;
    for (int ci = 0; ci < 13; ++ci) {
        const int g = cands[ci];
        if (K % (g * BKF) != 0) continue;
        const size_t need = (size_t)g * BB + 2 * (size_t)g * B + B + 1;
        if (need <= avail) { gz = g; break; }
    }
    const int KC = K / gz;

    float* ws      = (float*)d_ws;
    float* part    = ws;                          // gz * B*B
    float* spart   = part + (size_t)gz * BB;      // gz * B
    float* tpart   = spart + (size_t)gz * B;      // gz * B
    float* rowsum  = tpart + (size_t)gz * B;      // B
    int*   counter = (int*)(rowsum + B);          // 1

    const size_t lds_bytes = 2 * 2 * (size_t)ST * sizeof(unsigned short); // 64 KB
    gemm_dot_kernel<<<gz, 1024, lds_bytes, stream>>>(s_feat, t_feat, part,
                                                     spart, tpart, counter,
                                                     B, K, KC);

    tail_kernel<<<B, 256, 0, stream>>>(part, spart, tpart, t_logits, s_logits,
                                       labels, kp, tp, rowsum, counter, out,
                                       B, K, NL, gz);
}

// Round 8
// 268.614 us; speedup vs baseline: 1.0279x; 1.0279x over previous
//
#include <hip/hip_runtime.h>
#include <math.h>

// ---------------------------------------------------------------------------
// PatientDistillation: three losses.
//  out[0] = train_loss (CE over s_logits/labels)
//  out[1] = soft_loss  (KL(batchmean) at temperature T, * T^2)
//  out[2] = distill_loss (sum over rows of k smallest same-label sq dists / D)
//
// R7 lesson: 1 block/CU + barrier (compiler drains vmcnt(0) at s_barrier)
// = fully serial; prefetch is defeated. R3/R4 lesson: with a linear grid the
// 2x tile re-read is served cross-XCD (L3, ~4 TB/s ceiling). R8: 128x128
// tiles, 3 blocks/CU, XCD-aware decode (same-z quad-blocks co-located per
// XCD -> re-read hits that XCD's L2 at 34.5 TB/s; HBM sees each byte once).
// LP=40 LDS pitch: staging writes and frag ds_read_b128 both ~2-way (free).
// No device atomics in the GEMM (R2 lesson).
// ---------------------------------------------------------------------------

#define TM 128
#define TN 128
#define BK 32          // k-elems per iter; one 16x16x32 MFMA k-step
#define LP 40          // shorts per LDS row (80 B): 2-way banks, 16B-aligned
#define STH (TM * LP)  // shorts per matrix per stage (5120 = 10 KB)

typedef __attribute__((ext_vector_type(8))) short short8;   // 8 bf16 = 4 VGPR
typedef __attribute__((ext_vector_type(4))) float f32x4;

__device__ inline unsigned pack_bf16(float a, float b) {
    // round-to-nearest-even f32 -> bf16, packed pair
    unsigned ua = __float_as_uint(a), ub = __float_as_uint(b);
    ua = (ua + 0x7fffu + ((ua >> 16) & 1u)) >> 16;
    ub = (ub + 0x7fffu + ((ub >> 16) & 1u)) >> 16;
    return (ua & 0xffffu) | (ub << 16);
}

// ---------------- MFMA GEMM: dot partials + norm partials ------------------
// grid = mt*nt*gz blocks of 256 thr (4 waves, 2x2 quadrants of 64x64, each
// wave 4x4 tiles of 16x16x32 bf16 MFMA). XCD-aware decode keeps all (m,n)
// blocks of one z on one XCD. Register dbuf: write LDS(p) | issue loads(p+1)
// | barrier | compute(p) -- single barrier per iter is race-free because a
// wave reaching write(p^1) has passed the barrier that guarantees all waves
// finished reading p^1 (see R7).
__global__ __launch_bounds__(256, 3) void gemm_dot_kernel(const float* __restrict__ S,
                                                          const float* __restrict__ T,
                                                          float* __restrict__ part,   // [gz][B*B]
                                                          float* __restrict__ spart,  // [gz][B]
                                                          float* __restrict__ tpart,  // [gz][B]
                                                          int* __restrict__ counter,
                                                          int B, int K, int KC,
                                                          int mt, int nt, int gz) {
    extern __shared__ __align__(16) unsigned short smem[];  // 2*(As|Bs) = 40 KB

    const int tid   = threadIdx.x;
    const int blk   = blockIdx.x;
    const int tiles = mt * nt;

    if (blk == 0 && tid == 0) *counter = 0;   // replaces memset dispatch

    // ---- XCD-aware decode: same-z blocks co-resident on one XCD ----
    int z, mn;
    if ((gz & 7) == 0) {
        const int xcd  = blk & 7;
        const int slot = blk >> 3;
        const int zpx  = gz >> 3;       // z-values per XCD
        mn = slot % tiles;
        z  = xcd * zpx + slot / tiles;
    } else {
        z  = blk / tiles;
        mn = blk % tiles;
    }
    const int i0 = (mn / nt) * TM;
    const int j0 = (mn % nt) * TN;
    const int kbeg  = z * KC;
    const int iters = KC / BK;

    const int lane = tid & 63;
    const int wid  = tid >> 6;
    const int wm   = wid >> 1;
    const int wn   = wid & 1;
    const int l15  = lane & 15;
    const int quad = lane >> 4;

    // ---- staging coords: r = tid>>1 (row 0..127), h = tid&1 (k-half) ----
    const int r = tid >> 1;
    const int h = tid & 1;
    int gi = i0 + r; if (gi >= B) gi = B - 1;   // harmless duplicate
    int gj = j0 + r; if (gj >= B) gj = B - 1;
    const float* srcS = S + (size_t)gi * K + kbeg + h * 16;
    const float* srcT = T + (size_t)gj * K + kbeg + h * 16;
    const int woff = r * LP + h * 16;           // shorts; 16B-aligned

    // ---- frag read offsets (shorts) ----
    int aoff[4], boff[4];
    #pragma unroll
    for (int t = 0; t < 4; ++t) {
        aoff[t] = (wm * 64 + t * 16 + l15) * LP + quad * 8;
        boff[t] = (wn * 64 + t * 16 + l15) * LP + quad * 8;
    }

    const bool doS = ((mn % nt) == 0);   // n==0 blocks own S-norms
    const bool doT = ((mn / nt) == 0);   // m==0 blocks own T-norms

    f32x4 acc[4][4] = {};
    float pns = 0.f, pnt = 0.f;

    // ---- prologue loads (iter 0): 4 float4 per matrix per thread ----
    f32x4 s0 = *(const f32x4*)(srcS + 0);
    f32x4 s1 = *(const f32x4*)(srcS + 4);
    f32x4 s2 = *(const f32x4*)(srcS + 8);
    f32x4 s3 = *(const f32x4*)(srcS + 12);
    f32x4 t0 = *(const f32x4*)(srcT + 0);
    f32x4 t1 = *(const f32x4*)(srcT + 4);
    f32x4 t2 = *(const f32x4*)(srcT + 8);
    f32x4 t3 = *(const f32x4*)(srcT + 12);

    for (int it = 0; it < iters; ++it) {
        unsigned short* As = smem + (it & 1) * 2 * STH;
        unsigned short* Bs = As + STH;

        // ---- norms (block-uniform branches), pack, stage to LDS ----
        if (doS)
            pns += s0.x*s0.x + s0.y*s0.y + s0.z*s0.z + s0.w*s0.w
                 + s1.x*s1.x + s1.y*s1.y + s1.z*s1.z + s1.w*s1.w
                 + s2.x*s2.x + s2.y*s2.y + s2.z*s2.z + s2.w*s2.w
                 + s3.x*s3.x + s3.y*s3.y + s3.z*s3.z + s3.w*s3.w;
        if (doT)
            pnt += t0.x*t0.x + t0.y*t0.y + t0.z*t0.z + t0.w*t0.w
                 + t1.x*t1.x + t1.y*t1.y + t1.z*t1.z + t1.w*t1.w
                 + t2.x*t2.x + t2.y*t2.y + t2.z*t2.z + t2.w*t2.w
                 + t3.x*t3.x + t3.y*t3.y + t3.z*t3.z + t3.w*t3.w;
        uint4 pa0 = make_uint4(pack_bf16(s0.x, s0.y), pack_bf16(s0.z, s0.w),
                               pack_bf16(s1.x, s1.y), pack_bf16(s1.z, s1.w));
        uint4 pa1 = make_uint4(pack_bf16(s2.x, s2.y), pack_bf16(s2.z, s2.w),
                               pack_bf16(s3.x, s3.y), pack_bf16(s3.z, s3.w));
        uint4 pb0 = make_uint4(pack_bf16(t0.x, t0.y), pack_bf16(t0.z, t0.w),
                               pack_bf16(t1.x, t1.y), pack_bf16(t1.z, t1.w));
        uint4 pb1 = make_uint4(pack_bf16(t2.x, t2.y), pack_bf16(t2.z, t2.w),
                               pack_bf16(t3.x, t3.y), pack_bf16(t3.z, t3.w));
        *(uint4*)&As[woff]     = pa0;
        *(uint4*)&As[woff + 8] = pa1;
        *(uint4*)&Bs[woff]     = pb0;
        *(uint4*)&Bs[woff + 8] = pb1;

        // ---- issue next iter's loads (in flight across barrier+compute) ----
        if (it + 1 < iters) {
            const float* nS = srcS + (it + 1) * BK;
            const float* nT = srcT + (it + 1) * BK;
            s0 = *(const f32x4*)(nS + 0);
            s1 = *(const f32x4*)(nS + 4);
            s2 = *(const f32x4*)(nS + 8);
            s3 = *(const f32x4*)(nS + 12);
            t0 = *(const f32x4*)(nT + 0);
            t1 = *(const f32x4*)(nT + 4);
            t2 = *(const f32x4*)(nT + 8);
            t3 = *(const f32x4*)(nT + 12);
        }

        __syncthreads();

        // ---- compute: 4x4 tiles of 16x16x32 ----
        short8 bfr[4];
        #pragma unroll
        for (int ni = 0; ni < 4; ++ni)
            bfr[ni] = *(const short8*)&Bs[boff[ni]];
        #pragma unroll
        for (int mi = 0; mi < 4; ++mi) {
            short8 afr = *(const short8*)&As[aoff[mi]];
            #pragma unroll
            for (int ni = 0; ni < 4; ++ni)
                acc[mi][ni] = __builtin_amdgcn_mfma_f32_16x16x32_bf16(
                    afr, bfr[ni], acc[mi][ni], 0, 0, 0);
        }
    }

    // ---- dot partials: plain stores ----
    // C/D layout (16x16x32): col = lane&15, row = (lane>>4)*4 + reg
    float* outp = part + (size_t)z * B * B;
    #pragma unroll
    for (int mi = 0; mi < 4; ++mi) {
        #pragma unroll
        for (int ni = 0; ni < 4; ++ni) {
            #pragma unroll
            for (int rr = 0; rr < 4; ++rr) {
                const int ig = i0 + wm * 64 + mi * 16 + quad * 4 + rr;
                const int jg = j0 + wn * 64 + ni * 16 + l15;
                if (ig < B && jg < B)
                    outp[(size_t)ig * B + jg] = acc[mi][ni][rr];
            }
        }
    }

    // ---- norm partials: pair-reduce (2 threads/row), one store per row ----
    if (doS) {
        float v = pns + __shfl_xor(pns, 1, 64);
        if (h == 0 && i0 + r < B) spart[(size_t)z * B + i0 + r] = v;
    }
    if (doT) {
        float v = pnt + __shfl_xor(pnt, 1, 64);
        if (h == 0 && j0 + r < B) tpart[(size_t)z * B + j0 + r] = v;
    }
}

// ---------------- tail: z-reduce + norms + topk + CE/KL, one kernel --------
// grid = B blocks; block i handles row i. Thread j reduces part[:,i,j] with
// unroll-8 pipelined loads. Last block to finish finalizes out[0..2].
__global__ __launch_bounds__(256) void tail_kernel(const float* __restrict__ part,
                                                   const float* __restrict__ spart,
                                                   const float* __restrict__ tpart,
                                                   const float* __restrict__ t_logits,
                                                   const float* __restrict__ s_logits,
                                                   const int* __restrict__ labels,
                                                   const int* __restrict__ kp,
                                                   const int* __restrict__ tp,
                                                   float* __restrict__ rowsum,
                                                   int* __restrict__ counter,
                                                   float* __restrict__ out,
                                                   int B, int K, int NL, int gz) {
    const int i   = blockIdx.x;
    const int tid = threadIdx.x;
    const size_t BB = (size_t)B * B;

    __shared__ float svals[256];
    __shared__ float rv[256];
    __shared__ int   ri[256];
    __shared__ float red[4];
    __shared__ float snv;
    __shared__ int   lastf;

    // ---- s_nrm_i: threads cooperate over z
    float sp = 0.f;
    for (int z = tid; z < gz; z += 256) sp += spart[(size_t)z * B + i];
    #pragma unroll
    for (int off = 32; off > 0; off >>= 1) sp += __shfl_down(sp, off, 64);
    if ((tid & 63) == 0) red[tid >> 6] = sp;
    __syncthreads();
    if (tid == 0) snv = red[0] + red[1] + red[2] + red[3];
    __syncthreads();
    const float sn = snv;

    // ---- dt_j, tn_j: unroll-8 z-reduction (pipelined independent loads)
    float v = INFINITY;
    if (tid < B) {
        const float* pp = part + (size_t)i * B + tid;
        const float* tq = tpart + tid;
        float d0=0.f,d1=0.f,d2=0.f,d3=0.f,d4=0.f,d5=0.f,d6=0.f,d7=0.f;
        float tn = 0.f;
        int z = 0;
        for (; z + 8 <= gz; z += 8) {
            d0 += pp[(size_t)(z+0) * BB];
            d1 += pp[(size_t)(z+1) * BB];
            d2 += pp[(size_t)(z+2) * BB];
            d3 += pp[(size_t)(z+3) * BB];
            d4 += pp[(size_t)(z+4) * BB];
            d5 += pp[(size_t)(z+5) * BB];
            d6 += pp[(size_t)(z+6) * BB];
            d7 += pp[(size_t)(z+7) * BB];
            tn += tq[(size_t)(z+0) * B] + tq[(size_t)(z+1) * B]
                + tq[(size_t)(z+2) * B] + tq[(size_t)(z+3) * B]
                + tq[(size_t)(z+4) * B] + tq[(size_t)(z+5) * B]
                + tq[(size_t)(z+6) * B] + tq[(size_t)(z+7) * B];
        }
        float dt = ((d0+d1)+(d2+d3)) + ((d4+d5)+(d6+d7));
        for (; z < gz; ++z) {
            dt += pp[(size_t)z * BB];
            tn += tq[(size_t)z * B];
        }
        if (labels[i] == labels[tid])
            v = fmaxf(sn + tn - 2.0f * dt, 0.0f);
    }
    svals[tid] = v;
    __syncthreads();

    // ---- top-k smallest via LDS tournament
    const int k = kp[0];
    float sum = 0.0f;
    for (int it = 0; it < k; ++it) {
        rv[tid] = svals[tid];
        ri[tid] = tid;
        __syncthreads();
        #pragma unroll
        for (int s = 128; s > 0; s >>= 1) {
            if (tid < s) {
                if (rv[tid + s] < rv[tid]) { rv[tid] = rv[tid + s]; ri[tid] = ri[tid + s]; }
            }
            __syncthreads();
        }
        if (tid == 0) {
            if (rv[0] < 3.0e38f) sum += rv[0];
            svals[ri[0]] = INFINITY;
        }
        __syncthreads();
    }

    if (tid == 0) {
        rowsum[i] = sum;
        __threadfence();
        lastf = (atomicAdd(counter, 1) == B - 1) ? 1 : 0;
    }
    __syncthreads();
    if (!lastf) return;

    // ---- last block: finalize all three losses ----
    __threadfence();
    const float Tv = (float)tp[0];
    float rs = (tid < B) ? rowsum[tid] : 0.f;
    float ce = 0.0f, kl = 0.0f;
    for (int s = tid; s < B; s += 256) {
        const float* sl = s_logits + (size_t)s * NL;
        const float* tl = t_logits + (size_t)s * NL;
        float mx = -INFINITY;
        for (int c = 0; c < NL; ++c) mx = fmaxf(mx, sl[c]);
        float se = 0.0f;
        for (int c = 0; c < NL; ++c) se += expf(sl[c] - mx);
        ce += logf(se) + mx - sl[labels[s]];

        float mxs = -INFINITY, mxt = -INFINITY;
        for (int c = 0; c < NL; ++c) {
            mxs = fmaxf(mxs, sl[c] / Tv);
            mxt = fmaxf(mxt, tl[c] / Tv);
        }
        float ses = 0.0f, set = 0.0f;
        for (int c = 0; c < NL; ++c) {
            ses += expf(sl[c] / Tv - mxs);
            set += expf(tl[c] / Tv - mxt);
        }
        float lses = logf(ses) + mxs;
        float lset = logf(set) + mxt;
        for (int c = 0; c < NL; ++c) {
            float lst = tl[c] / Tv - lset;
            float ls  = sl[c] / Tv - lses;
            kl += expf(lst) * (lst - ls);
        }
    }
    #pragma unroll
    for (int off = 32; off > 0; off >>= 1) {
        ce += __shfl_down(ce, off, 64);
        kl += __shfl_down(kl, off, 64);
        rs += __shfl_down(rs, off, 64);
    }
    __shared__ float wce[4], wkl[4], wrs[4];
    if ((tid & 63) == 0) { wce[tid >> 6] = ce; wkl[tid >> 6] = kl; wrs[tid >> 6] = rs; }
    __syncthreads();
    if (tid == 0) {
        out[0] = (wce[0] + wce[1] + wce[2] + wce[3]) / (float)B;
        out[1] = (wkl[0] + wkl[1] + wkl[2] + wkl[3]) / (float)B * Tv * Tv;
        out[2] = (wrs[0] + wrs[1] + wrs[2] + wrs[3]) / (float)K;
    }
}

// ---------------------------------------------------------------------------
extern "C" void kernel_launch(void* const* d_in, const int* in_sizes, int n_in,
                              void* d_out, int out_size, void* d_ws, size_t ws_size,
                              hipStream_t stream) {
    const float* t_logits = (const float*)d_in[0];
    const float* s_logits = (const float*)d_in[1];
    const float* t_feat   = (const float*)d_in[2];
    const float* s_feat   = (const float*)d_in[3];
    const int*   labels   = (const int*)d_in[4];
    const int*   kp       = (const int*)d_in[5];
    const int*   tp       = (const int*)d_in[6];
    float* out = (float*)d_out;

    const int B  = in_sizes[4];          // 256
    const int NL = in_sizes[0] / B;      // 2
    const int K  = in_sizes[2] / B;      // S*H = 98304
    const size_t BB = (size_t)B * B;

    const int mt = (B + TM - 1) / TM;    // 2
    const int nt = (B + TN - 1) / TN;    // 2

    // split-K: prefer gz=192 (grid = 4*192 = 768 = 3 blocks/CU); need
    // K % (gz*BK) == 0 and workspace fit.
    const size_t avail = ws_size / 4;
    const int cands[] = {192, 128, 96, 64, 48, 32, 24, 16, 12, 8, 6, 4, 2, 1};
    int gz = 1;
    for (int ci = 0; ci < 14; ++ci) {
        const int g = cands[ci];
        if (K % (g * BK) != 0) continue;
        const size_t need = (size_t)g * BB + 2 * (size_t)g * B + B + 1;
        if (need <= avail) { gz = g; break; }
    }
    const int KC = K / gz;

    float* ws      = (float*)d_ws;
    float* part    = ws;                          // gz * B*B
    float* spart   = part + (size_t)gz * BB;      // gz * B
    float* tpart   = spart + (size_t)gz * B;      // gz * B
    float* rowsum  = tpart + (size_t)gz * B;      // B
    int*   counter = (int*)(rowsum + B);          // 1

    const int grid = mt * nt * gz;
    const size_t lds_bytes = 2 * 2 * (size_t)STH * sizeof(unsigned short); // 40 KB
    gemm_dot_kernel<<<grid, 256, lds_bytes, stream>>>(s_feat, t_feat, part,
                                                      spart, tpart, counter,
                                                      B, K, KC, mt, nt, gz);

    tail_kernel<<<B, 256, 0, stream>>>(part, spart, tpart, t_logits, s_logits,
                                       labels, kp, tp, rowsum, counter, out,
                                       B, K, NL, gz);
}